// Round 5
// baseline (334.598 us; speedup 1.0000x reference)
//
#include <hip/hip_runtime.h>
#include <hip/hip_bf16.h>

#define T_TOK 8192
#define DMODEL 1024
#define NEXP 128
#define CAP 256

typedef short s16x8 __attribute__((ext_vector_type(8)));
typedef float f32x4 __attribute__((ext_vector_type(4)));

__device__ __forceinline__ unsigned short f2bf(float f) {
    return __bfloat16_as_ushort(__float2bfloat16(f));
}
__device__ __forceinline__ unsigned int pk2(unsigned short lo, unsigned short hi) {
    return (unsigned int)lo | ((unsigned int)hi << 16);
}
__device__ __forceinline__ float bf2f(unsigned short u) {
    union { unsigned int u; float f; } v; v.u = ((unsigned int)u) << 16; return v.f;
}

// ---------------- zero init: expert counters only ----------------
__global__ __launch_bounds__(128) void zero_cnt(int* __restrict__ cnt) {
    cnt[threadIdx.x] = 0;
}

// ---------------- pass A: fp32 logits, top-4 candidates, x->bf16 ----------------
// block = 512 threads, 32 tokens per block, grid = 256
__global__ __launch_bounds__(512) void gate32_kernel(
    const float* __restrict__ x, const float* __restrict__ wg,
    unsigned short* __restrict__ xb, int* __restrict__ cand4)
{
    __shared__ float xs[32][36];     // [tok][k]
    __shared__ float wgs[32][128];   // [k][e]
    __shared__ float ls[128][33];    // [e][tok] fp32 logits

    int tid = threadIdx.x;
    int tok0 = blockIdx.x * 32;

    int tg = tid >> 6;          // 0..7  token phase
    int eg = tid & 63;          // expert pair base = eg*2
    int xtok = tid >> 4;        // 0..31 staging row
    int xoff = (tid & 15) * 2;  // staging col (2 floats)
    int wrow = tid >> 4;        // 0..31
    int wcol = (tid & 15) * 8;  // 8 floats

    float acc[4][2];
    #pragma unroll
    for (int j = 0; j < 4; j++) { acc[j][0] = 0.f; acc[j][1] = 0.f; }

    for (int k0 = 0; k0 < DMODEL; k0 += 32) {
        float2 xv = *(const float2*)(x + (size_t)(tok0 + xtok) * DMODEL + k0 + xoff);
        float4 wv4[2];
        #pragma unroll
        for (int c = 0; c < 2; c++)
            wv4[c] = *(const float4*)(wg + (size_t)(k0 + wrow) * NEXP + wcol + c * 4);

        __syncthreads();
        *(float2*)&xs[xtok][xoff] = xv;
        *(unsigned int*)(xb + (size_t)(tok0 + xtok) * DMODEL + k0 + xoff) = pk2(f2bf(xv.x), f2bf(xv.y));
        #pragma unroll
        for (int c = 0; c < 2; c++) *(float4*)&wgs[wrow][wcol + c * 4] = wv4[c];
        __syncthreads();

        #pragma unroll
        for (int k = 0; k < 32; k++) {
            float2 wv = *(const float2*)&wgs[k][eg * 2];
            #pragma unroll
            for (int j = 0; j < 4; j++) {
                float xd = xs[j * 8 + tg][k];
                acc[j][0] = fmaf(xd, wv.x, acc[j][0]);
                acc[j][1] = fmaf(xd, wv.y, acc[j][1]);
            }
        }
    }

    __syncthreads();
    #pragma unroll
    for (int j = 0; j < 4; j++) {
        ls[eg * 2][j * 8 + tg]     = acc[j][0];
        ls[eg * 2 + 1][j * 8 + tg] = acc[j][1];
    }
    __syncthreads();

    if (tid < 32) {
        int tok = tid;
        float m0 = -1e30f, m1 = -1e30f, m2 = -1e30f, m3 = -1e30f;
        int i0 = -1, i1 = -1, i2 = -1, i3 = -1;
        for (int e = 0; e < NEXP; e++) {
            float v = ls[e][tok];
            if (v > m0)      { m3=m2;i3=i2; m2=m1;i2=i1; m1=m0;i1=i0; m0=v;i0=e; }
            else if (v > m1) { m3=m2;i3=i2; m2=m1;i2=i1; m1=v;i1=e; }
            else if (v > m2) { m3=m2;i3=i2; m2=v;i2=e; }
            else if (v > m3) { m3=v;i3=e; }
        }
        int gtok = tok0 + tok;
        cand4[gtok * 4 + 0] = i0;
        cand4[gtok * 4 + 1] = i1;
        cand4[gtok * 4 + 2] = i2;
        cand4[gtok * 4 + 3] = i3;
    }
}

// ---------------- pass B: fp64 refine of 4 candidates, slot assignment ----------------
// one wave per token; block = 512 (8 waves), grid = 1024
__global__ __launch_bounds__(512) void refine_kernel(
    const float* __restrict__ x, const float* __restrict__ wg,
    const int* __restrict__ cand4, int* __restrict__ cnt,
    int* __restrict__ tokList, int* __restrict__ tokSlot,
    float* __restrict__ tokGate)
{
    int lane = threadIdx.x & 63;
    int wave = threadIdx.x >> 6;
    int tok = blockIdx.x * 8 + wave;

    int c0 = cand4[tok * 4 + 0], c1 = cand4[tok * 4 + 1];
    int c2 = cand4[tok * 4 + 2], c3 = cand4[tok * 4 + 3];

    double a0 = 0.0, a1 = 0.0, a2 = 0.0, a3 = 0.0;
    const float* xr = x + (size_t)tok * DMODEL;
    #pragma unroll 4
    for (int i = 0; i < 16; i++) {
        int k = i * 64 + lane;
        double xv = (double)xr[k];
        const float* wr = wg + (size_t)k * NEXP;
        a0 = fma(xv, (double)wr[c0], a0);
        a1 = fma(xv, (double)wr[c1], a1);
        a2 = fma(xv, (double)wr[c2], a2);
        a3 = fma(xv, (double)wr[c3], a3);
    }
    // wave reduction
    #pragma unroll
    for (int off = 32; off > 0; off >>= 1) {
        a0 += __shfl_down(a0, off);
        a1 += __shfl_down(a1, off);
        a2 += __shfl_down(a2, off);
        a3 += __shfl_down(a3, off);
    }

    if (lane == 0) {
        double v[4] = {a0, a1, a2, a3};
        int   id[4] = {c0, c1, c2, c3};
        // top-1: max value, lowest index on tie
        int b1 = 0;
        #pragma unroll
        for (int j = 1; j < 4; j++)
            if (v[j] > v[b1] || (v[j] == v[b1] && id[j] < id[b1])) b1 = j;
        // top-2 among the rest
        int b2 = -1;
        #pragma unroll
        for (int j = 0; j < 4; j++) {
            if (j == b1) continue;
            if (b2 < 0 || v[j] > v[b2] || (v[j] == v[b2] && id[j] < id[b2])) b2 = j;
        }
        int i1 = id[b1], i2 = id[b2];
        double ed = exp(v[b2] - v[b1]);            // <= 1
        float g1 = (float)(1.0 / (1.0 + ed));
        float g2 = (float)(ed / (1.0 + ed));

        int s1 = atomicAdd(&cnt[i1], 1);
        int slot1 = -1;
        if (s1 < CAP) { slot1 = i1 * CAP + s1; tokList[slot1] = tok; }
        int s2 = atomicAdd(&cnt[i2], 1);
        int slot2 = -1;
        if (s2 < CAP) { slot2 = i2 * CAP + s2; tokList[slot2] = tok; }
        tokSlot[2 * tok]     = slot1;
        tokSlot[2 * tok + 1] = slot2;
        tokGate[2 * tok]     = g1;
        tokGate[2 * tok + 1] = g2;
    }
}

// ---------------- grouped expert GEMM -> yb bf16 (software-pipelined) ----------------
// grid = 128 experts * 8 n-blocks = 1024, block = 512 (8 waves)
// BM=256 (capacity), BN=128, BK=64.
#define LDS_STRIDE 72
__global__ __launch_bounds__(512, 4) void moe_gemm(
    const float* __restrict__ we, const unsigned short* __restrict__ xb,
    const int* __restrict__ cnt, const int* __restrict__ tokList,
    unsigned short* __restrict__ ybh)
{
    __shared__ unsigned short As[256 * LDS_STRIDE];  // 36 KB
    __shared__ unsigned short Bs[128 * LDS_STRIDE];  // 18 KB

    int b = blockIdx.x;
    int xcd = b & 7;
    int jj = b >> 3;
    int e = xcd * 16 + (jj >> 3);   // 8 n-blocks of one expert land on one XCD
    int nq = jj & 7;
    int nb = nq * 128;

    int count = cnt[e];
    if (count > CAP) count = CAP;

    int tid = threadIdx.x;
    int lane = tid & 63, wave = tid >> 6;
    int band = wave >> 1;   // 0..3 -> rows band*64..
    int nh = wave & 1;      // 0..1 -> cols nh*64..

    int mcount = count - band * 64;
    int nmf = (mcount + 15) >> 4;
    if (nmf < 0) nmf = 0;
    if (nmf > 4) nmf = 4;

    f32x4 acc[4][4] = {};

    int ar = tid >> 1, ah = tid & 1;
    int atok = -1;
    if (ar < count) atok = tokList[e * CAP + ar];
    const unsigned short* asrc = xb + ((size_t)(atok < 0 ? 0 : atok) << 10) + ah * 32;
    unsigned short* adst = As + ar * LDS_STRIDE + ah * 32;

    int bn = tid & 127, bkq = tid >> 7;
    const float* bsrc = we + ((size_t)e << 20) + (size_t)(bkq * 16) * DMODEL + nb + bn;
    unsigned short* bdst = Bs + bn * LDS_STRIDE + bkq * 16;

    uint4 fa0 = {0,0,0,0}, fa1 = {0,0,0,0}, fa2 = {0,0,0,0}, fa3 = {0,0,0,0};
    float fb[16];
    if (atok >= 0) {
        const uint4* p = (const uint4*)asrc;
        fa0 = p[0]; fa1 = p[1]; fa2 = p[2]; fa3 = p[3];
    }
    {
        const float* wp = bsrc;
        #pragma unroll
        for (int i = 0; i < 16; i++) fb[i] = wp[(size_t)i * DMODEL];
    }

    for (int t = 0; t < 16; ++t) {
        uint4 b0, b1;
        {
            unsigned short h[16];
            #pragma unroll
            for (int i = 0; i < 16; i++) h[i] = f2bf(fb[i]);
            b0.x = pk2(h[0], h[1]);   b0.y = pk2(h[2], h[3]);
            b0.z = pk2(h[4], h[5]);   b0.w = pk2(h[6], h[7]);
            b1.x = pk2(h[8], h[9]);   b1.y = pk2(h[10], h[11]);
            b1.z = pk2(h[12], h[13]); b1.w = pk2(h[14], h[15]);
        }

        __syncthreads();
        *(uint4*)adst        = fa0;
        *(uint4*)(adst + 8)  = fa1;
        *(uint4*)(adst + 16) = fa2;
        *(uint4*)(adst + 24) = fa3;
        *(uint4*)bdst        = b0;
        *(uint4*)(bdst + 8)  = b1;
        __syncthreads();

        if (t < 15) {
            int k1 = (t + 1) * 64;
            if (atok >= 0) {
                const uint4* p = (const uint4*)(asrc + k1);
                fa0 = p[0]; fa1 = p[1]; fa2 = p[2]; fa3 = p[3];
            }
            const float* wp = bsrc + (size_t)k1 * DMODEL;
            #pragma unroll
            for (int i = 0; i < 16; i++) fb[i] = wp[(size_t)i * DMODEL];
        }

        #pragma unroll
        for (int kk = 0; kk < 64; kk += 32) {
            int kr = kk + ((lane >> 4) << 3);
            s16x8 bf[4];
            const unsigned short* bbase = Bs + (size_t)(nh * 64 + (lane & 15)) * LDS_STRIDE + kr;
            #pragma unroll
            for (int nf = 0; nf < 4; nf++)
                bf[nf] = *(const s16x8*)(bbase + nf * 16 * LDS_STRIDE);
            const unsigned short* abase = As + (size_t)(band * 64 + (lane & 15)) * LDS_STRIDE + kr;
            #pragma unroll
            for (int mf = 0; mf < 4; mf++) {
                if (mf < nmf) {
                    s16x8 af = *(const s16x8*)(abase + mf * 16 * LDS_STRIDE);
                    #pragma unroll
                    for (int nf = 0; nf < 4; nf++)
                        acc[mf][nf] = __builtin_amdgcn_mfma_f32_16x16x32_bf16(af, bf[nf], acc[mf][nf], 0, 0, 0);
                }
            }
        }
    }

    #pragma unroll
    for (int mf = 0; mf < 4; mf++) {
        if (mf < nmf) {
            #pragma unroll
            for (int j4 = 0; j4 < 4; j4++) {
                int r = band * 64 + mf * 16 + ((lane >> 4) << 2) + j4;
                if (r < count) {
                    unsigned short* yrow = ybh + (((size_t)(e * CAP + r)) << 10) + nb + nh * 64 + (lane & 15);
                    #pragma unroll
                    for (int nf = 0; nf < 4; nf++)
                        yrow[nf * 16] = f2bf(acc[mf][nf][j4]);
                }
            }
        }
    }
}

// ---------------- combine: out[tok] = g1*yb[slot1] + g2*yb[slot2] ----------------
__global__ __launch_bounds__(256) void combine_kernel(
    const unsigned short* __restrict__ ybh, const int* __restrict__ tokSlot,
    const float* __restrict__ tokGate, float* __restrict__ out)
{
    int tid = threadIdx.x;
    int tok = blockIdx.x * 4 + (tid >> 6);
    int lane = tid & 63;
    int sA = tokSlot[2 * tok], sB = tokSlot[2 * tok + 1];
    float gA = tokGate[2 * tok], gB = tokGate[2 * tok + 1];

    uint4 va[2] = {{0,0,0,0},{0,0,0,0}}, vb[2] = {{0,0,0,0},{0,0,0,0}};
    if (sA >= 0) {
        const uint4* p = (const uint4*)(ybh + ((size_t)sA << 10)) + lane * 2;
        va[0] = p[0]; va[1] = p[1];
    }
    if (sB >= 0) {
        const uint4* p = (const uint4*)(ybh + ((size_t)sB << 10)) + lane * 2;
        vb[0] = p[0]; vb[1] = p[1];
    }
    float4* o4 = (float4*)(out + ((size_t)tok << 10)) + lane * 4;
    #pragma unroll
    for (int h = 0; h < 2; h++) {
        const unsigned int* ua = (const unsigned int*)&va[h];
        const unsigned int* ub = (const unsigned int*)&vb[h];
        #pragma unroll
        for (int q = 0; q < 2; q++) {
            float4 o;
            unsigned int a0 = ua[q * 2], a1 = ua[q * 2 + 1];
            unsigned int b0 = ub[q * 2], b1 = ub[q * 2 + 1];
            o.x = gA * bf2f((unsigned short)(a0 & 0xFFFF)) + gB * bf2f((unsigned short)(b0 & 0xFFFF));
            o.y = gA * bf2f((unsigned short)(a0 >> 16))    + gB * bf2f((unsigned short)(b0 >> 16));
            o.z = gA * bf2f((unsigned short)(a1 & 0xFFFF)) + gB * bf2f((unsigned short)(b1 & 0xFFFF));
            o.w = gA * bf2f((unsigned short)(a1 >> 16))    + gB * bf2f((unsigned short)(b1 >> 16));
            o4[h * 2 + q] = o;
        }
    }
}

extern "C" void kernel_launch(void* const* d_in, const int* in_sizes, int n_in,
                              void* d_out, int out_size, void* d_ws, size_t ws_size,
                              hipStream_t stream) {
    const float* x  = (const float*)d_in[0];   // [4,2048,1024]
    const float* wg = (const float*)d_in[1];   // [1024,128]
    const float* we = (const float*)d_in[2];   // [128,1024,1024]
    float* out = (float*)d_out;                // [4,2048,1024]

    char* ws = (char*)d_ws;
    int*   cnt     = (int*)ws;                              // 512 B
    int*   tokList = (int*)(ws + 1024);                     // 128 KB
    int*   tokSlot = (int*)(ws + 1024 + 131072);            // 64 KB
    float* tokGate = (float*)(ws + 1024 + 131072 + 65536);  // 64 KB
    int*   cand4   = (int*)(ws + 262144);                   // 128 KB (token -> 4 candidate experts)
    unsigned short* xb  = (unsigned short*)(ws + 524288);   // 16 MB bf16 copy of x
    unsigned short* ybh = (unsigned short*)(ws + 524288 + 16777216);  // 32 MB expert outputs bf16

    zero_cnt<<<1, 128, 0, stream>>>(cnt);
    gate32_kernel<<<256, 512, 0, stream>>>(x, wg, xb, cand4);
    refine_kernel<<<1024, 512, 0, stream>>>(x, wg, cand4, cnt, tokList, tokSlot, tokGate);
    moe_gemm<<<1024, 512, 0, stream>>>(we, xb, cnt, tokList, ybh);
    combine_kernel<<<2048, 256, 0, stream>>>(ybh, tokSlot, tokGate, out);
}

// Round 7
// 262.282 us; speedup vs baseline: 1.2757x; 1.2757x over previous
//
#include <hip/hip_runtime.h>
#include <hip/hip_bf16.h>

#define T_TOK 8192
#define DMODEL 1024
#define NEXP 128
#define CAP 256

typedef short s16x8 __attribute__((ext_vector_type(8)));
typedef float f32x4 __attribute__((ext_vector_type(4)));

__device__ __forceinline__ unsigned short f2bf(float f) {
    return __bfloat16_as_ushort(__float2bfloat16(f));
}
__device__ __forceinline__ unsigned int pk2(unsigned short lo, unsigned short hi) {
    return (unsigned int)lo | ((unsigned int)hi << 16);
}
__device__ __forceinline__ float bf2f(unsigned short u) {
    union { unsigned int u; float f; } v; v.u = ((unsigned int)u) << 16; return v.f;
}

// ---------------- prep: x->xb bf16, wg->wgT fp32 transpose, cnt zero ----------------
__global__ __launch_bounds__(256) void prep_kernel(
    const float* __restrict__ x, const float* __restrict__ wg,
    unsigned short* __restrict__ xb, float* __restrict__ wgT, int* __restrict__ cnt)
{
    int gid = blockIdx.x;
    int tid = threadIdx.x;
    if (gid < 2048) {
        const float4* x4 = (const float4*)x;
        for (int g = gid * 256 + tid; g < (T_TOK * DMODEL) / 4; g += 2048 * 256) {
            float4 v = x4[g];
            uint2 o;
            o.x = pk2(f2bf(v.x), f2bf(v.y));
            o.y = pk2(f2bf(v.z), f2bf(v.w));
            *(uint2*)(xb + (size_t)g * 4) = o;
        }
    } else if (gid == 2048) {
        if (tid < NEXP) cnt[tid] = 0;
    } else {
        int kb = gid - 2049;          // 0..31
        int e = tid & 127;
        int kh = tid >> 7;            // 0..1
        #pragma unroll
        for (int kk = 0; kk < 16; kk++) {
            int k = kb * 32 + kh * 16 + kk;
            wgT[(size_t)e * DMODEL + k] = wg[(size_t)k * NEXP + e];
        }
    }
}

// ---------------- gate: MFMA logits (bf16) -> top-8 -> fused fp64 refine ----------------
// grid = 128 blocks x 512 thr (8 waves); 64 tokens/block, 128 experts, K tiled by 64
#define GLS 72
#define LCOL 133
__global__ __launch_bounds__(512) void gate_mfma(
    const float* __restrict__ x, const float* __restrict__ wg,
    const float* __restrict__ wgT, const unsigned short* __restrict__ xb,
    int* __restrict__ cnt, int* __restrict__ tokList,
    int* __restrict__ tokSlot, float* __restrict__ tokGate)
{
    __shared__ __align__(16) char smem[36992];
    unsigned short* As = (unsigned short*)smem;            // 64*72*2  = 9216
    unsigned short* Bs = (unsigned short*)(smem + 9216);   // 128*72*2 = 18432 (ends 27648)
    float* ls = (float*)smem;                              // 64*133*4 = 34048 (after k-loop)
    int*   ci = (int*)(smem + 34048);                      // 64*8*4   = 2048  (ends 36096)

    int tid = threadIdx.x, lane = tid & 63, wave = tid >> 6;
    int tok0 = blockIdx.x * 64;
    int nh = wave;                  // expert group of 16

    f32x4 acc[4] = {};

    // A staging: row ar (token), 8-short octet aq
    int ar = tid >> 3, aq = tid & 7;
    const unsigned short* asrc = xb + ((size_t)(tok0 + ar) << 10) + aq * 8;
    unsigned short* adst = As + ar * GLS + aq * 8;
    // B staging: expert bn, k-quarter bkq
    int bn = tid & 127, bkq = tid >> 7;
    const float* bsrc = wg + (size_t)(bkq * 16) * NEXP + bn;
    unsigned short* bdst = Bs + bn * GLS + bkq * 16;

    for (int t = 0; t < 16; ++t) {
        uint4 av = *(const uint4*)(asrc + t * 64);
        float f[16];
        const float* wp = bsrc + (size_t)t * 64 * NEXP;
        #pragma unroll
        for (int i = 0; i < 16; i++) f[i] = wp[(size_t)i * NEXP];
        uint4 b0, b1;
        {
            unsigned short h[16];
            #pragma unroll
            for (int i = 0; i < 16; i++) h[i] = f2bf(f[i]);
            b0.x = pk2(h[0], h[1]);   b0.y = pk2(h[2], h[3]);
            b0.z = pk2(h[4], h[5]);   b0.w = pk2(h[6], h[7]);
            b1.x = pk2(h[8], h[9]);   b1.y = pk2(h[10], h[11]);
            b1.z = pk2(h[12], h[13]); b1.w = pk2(h[14], h[15]);
        }
        __syncthreads();
        *(uint4*)adst = av;
        *(uint4*)bdst = b0;
        *(uint4*)(bdst + 8) = b1;
        __syncthreads();

        #pragma unroll
        for (int kk = 0; kk < 64; kk += 32) {
            int kr = kk + ((lane >> 4) << 3);
            s16x8 bf = *(const s16x8*)(Bs + (size_t)(nh * 16 + (lane & 15)) * GLS + kr);
            #pragma unroll
            for (int mf = 0; mf < 4; mf++) {
                s16x8 af = *(const s16x8*)(As + (size_t)(mf * 16 + (lane & 15)) * GLS + kr);
                acc[mf] = __builtin_amdgcn_mfma_f32_16x16x32_bf16(af, bf, acc[mf], 0, 0, 0);
            }
        }
    }
    __syncthreads();   // staging dead; reuse LDS for logits

    #pragma unroll
    for (int mf = 0; mf < 4; mf++)
        #pragma unroll
        for (int j = 0; j < 4; j++)
            ls[(size_t)(mf * 16 + ((lane >> 4) << 2) + j) * LCOL + nh * 16 + (lane & 15)] = acc[mf][j];
    __syncthreads();

    // top-8 scan: thread t owns token t
    if (tid < 64) {
        float m[8]; int id8[8];
        #pragma unroll
        for (int j = 0; j < 8; j++) { m[j] = -1e30f; id8[j] = 0; }
        const float* row = ls + (size_t)tid * LCOL;
        for (int e = 0; e < NEXP; e++) {
            float v = row[e];
            if (v > m[7]) {
                int j = 7;
                while (j > 0 && v > m[j - 1]) { m[j] = m[j - 1]; id8[j] = id8[j - 1]; j--; }
                m[j] = v; id8[j] = e;
            }
        }
        #pragma unroll
        for (int j = 0; j < 8; j++) ci[tid * 8 + j] = id8[j];
    }
    __syncthreads();

    // fused fp64 refine: wave w handles tokens w*8..w*8+7
    for (int tt = 0; tt < 8; ++tt) {
        int t = wave * 8 + tt;
        int gtok = tok0 + t;
        int c0 = ci[t*8+0], c1 = ci[t*8+1], c2 = ci[t*8+2], c3 = ci[t*8+3];
        int c4 = ci[t*8+4], c5 = ci[t*8+5], c6 = ci[t*8+6], c7 = ci[t*8+7];
        double a0=0, a1=0, a2=0, a3=0, a4=0, a5=0, a6=0, a7=0;
        const float* xr = x + ((size_t)gtok << 10);
        #pragma unroll 4
        for (int i = 0; i < 16; ++i) {
            int k = i * 64 + lane;
            double xd = (double)xr[k];
            a0 = fma(xd, (double)wgT[(size_t)c0 * DMODEL + k], a0);
            a1 = fma(xd, (double)wgT[(size_t)c1 * DMODEL + k], a1);
            a2 = fma(xd, (double)wgT[(size_t)c2 * DMODEL + k], a2);
            a3 = fma(xd, (double)wgT[(size_t)c3 * DMODEL + k], a3);
            a4 = fma(xd, (double)wgT[(size_t)c4 * DMODEL + k], a4);
            a5 = fma(xd, (double)wgT[(size_t)c5 * DMODEL + k], a5);
            a6 = fma(xd, (double)wgT[(size_t)c6 * DMODEL + k], a6);
            a7 = fma(xd, (double)wgT[(size_t)c7 * DMODEL + k], a7);
        }
        #pragma unroll
        for (int off = 32; off > 0; off >>= 1) {
            a0 += __shfl_xor(a0, off); a1 += __shfl_xor(a1, off);
            a2 += __shfl_xor(a2, off); a3 += __shfl_xor(a3, off);
            a4 += __shfl_xor(a4, off); a5 += __shfl_xor(a5, off);
            a6 += __shfl_xor(a6, off); a7 += __shfl_xor(a7, off);
        }
        if (lane == 0) {
            double av[8] = {a0,a1,a2,a3,a4,a5,a6,a7};
            int    cv[8] = {c0,c1,c2,c3,c4,c5,c6,c7};
            double v1 = av[0]; int i1 = cv[0];
            #pragma unroll
            for (int j = 1; j < 8; j++)
                if (av[j] > v1 || (av[j] == v1 && cv[j] < i1)) { v1 = av[j]; i1 = cv[j]; }
            double v2 = -1e300; int i2 = 0x7FFFFFFF;
            #pragma unroll
            for (int j = 0; j < 8; j++) {
                if (cv[j] == i1) continue;
                if (av[j] > v2 || (av[j] == v2 && cv[j] < i2)) { v2 = av[j]; i2 = cv[j]; }
            }
            double ed = exp(v2 - v1);            // <= 1
            float g1 = (float)(1.0 / (1.0 + ed));
            float g2 = (float)(ed / (1.0 + ed));
            int s1 = atomicAdd(&cnt[i1], 1);
            int slot1 = -1;
            if (s1 < CAP) { slot1 = i1 * CAP + s1; tokList[slot1] = gtok; }
            int s2 = atomicAdd(&cnt[i2], 1);
            int slot2 = -1;
            if (s2 < CAP) { slot2 = i2 * CAP + s2; tokList[slot2] = gtok; }
            tokSlot[2 * gtok]     = slot1;
            tokSlot[2 * gtok + 1] = slot2;
            tokGate[2 * gtok]     = g1;
            tokGate[2 * gtok + 1] = g2;
        }
    }
}

// ---------------- grouped expert GEMM -> yb bf16 (unchanged) ----------------
#define LDS_STRIDE 72
__global__ __launch_bounds__(512, 4) void moe_gemm(
    const float* __restrict__ we, const unsigned short* __restrict__ xb,
    const int* __restrict__ cnt, const int* __restrict__ tokList,
    unsigned short* __restrict__ ybh)
{
    __shared__ unsigned short As[256 * LDS_STRIDE];  // 36 KB
    __shared__ unsigned short Bs[128 * LDS_STRIDE];  // 18 KB

    int b = blockIdx.x;
    int xcd = b & 7;
    int jj = b >> 3;
    int e = xcd * 16 + (jj >> 3);
    int nq = jj & 7;
    int nb = nq * 128;

    int count = cnt[e];
    if (count > CAP) count = CAP;

    int tid = threadIdx.x;
    int lane = tid & 63, wave = tid >> 6;
    int band = wave >> 1;
    int nh = wave & 1;

    int mcount = count - band * 64;
    int nmf = (mcount + 15) >> 4;
    if (nmf < 0) nmf = 0;
    if (nmf > 4) nmf = 4;

    f32x4 acc[4][4] = {};

    int ar = tid >> 1, ah = tid & 1;
    int atok = -1;
    if (ar < count) atok = tokList[e * CAP + ar];
    const unsigned short* asrc = xb + ((size_t)(atok < 0 ? 0 : atok) << 10) + ah * 32;
    unsigned short* adst = As + ar * LDS_STRIDE + ah * 32;

    int bn = tid & 127, bkq = tid >> 7;
    const float* bsrc = we + ((size_t)e << 20) + (size_t)(bkq * 16) * DMODEL + nb + bn;
    unsigned short* bdst = Bs + bn * LDS_STRIDE + bkq * 16;

    uint4 fa0 = {0,0,0,0}, fa1 = {0,0,0,0}, fa2 = {0,0,0,0}, fa3 = {0,0,0,0};
    float fb[16];
    if (atok >= 0) {
        const uint4* p = (const uint4*)asrc;
        fa0 = p[0]; fa1 = p[1]; fa2 = p[2]; fa3 = p[3];
    }
    {
        const float* wp = bsrc;
        #pragma unroll
        for (int i = 0; i < 16; i++) fb[i] = wp[(size_t)i * DMODEL];
    }

    for (int t = 0; t < 16; ++t) {
        uint4 b0, b1;
        {
            unsigned short h[16];
            #pragma unroll
            for (int i = 0; i < 16; i++) h[i] = f2bf(fb[i]);
            b0.x = pk2(h[0], h[1]);   b0.y = pk2(h[2], h[3]);
            b0.z = pk2(h[4], h[5]);   b0.w = pk2(h[6], h[7]);
            b1.x = pk2(h[8], h[9]);   b1.y = pk2(h[10], h[11]);
            b1.z = pk2(h[12], h[13]); b1.w = pk2(h[14], h[15]);
        }

        __syncthreads();
        *(uint4*)adst        = fa0;
        *(uint4*)(adst + 8)  = fa1;
        *(uint4*)(adst + 16) = fa2;
        *(uint4*)(adst + 24) = fa3;
        *(uint4*)bdst        = b0;
        *(uint4*)(bdst + 8)  = b1;
        __syncthreads();

        if (t < 15) {
            int k1 = (t + 1) * 64;
            if (atok >= 0) {
                const uint4* p = (const uint4*)(asrc + k1);
                fa0 = p[0]; fa1 = p[1]; fa2 = p[2]; fa3 = p[3];
            }
            const float* wp = bsrc + (size_t)k1 * DMODEL;
            #pragma unroll
            for (int i = 0; i < 16; i++) fb[i] = wp[(size_t)i * DMODEL];
        }

        #pragma unroll
        for (int kk = 0; kk < 64; kk += 32) {
            int kr = kk + ((lane >> 4) << 3);
            s16x8 bf[4];
            const unsigned short* bbase = Bs + (size_t)(nh * 64 + (lane & 15)) * LDS_STRIDE + kr;
            #pragma unroll
            for (int nf = 0; nf < 4; nf++)
                bf[nf] = *(const s16x8*)(bbase + nf * 16 * LDS_STRIDE);
            const unsigned short* abase = As + (size_t)(band * 64 + (lane & 15)) * LDS_STRIDE + kr;
            #pragma unroll
            for (int mf = 0; mf < 4; mf++) {
                if (mf < nmf) {
                    s16x8 af = *(const s16x8*)(abase + mf * 16 * LDS_STRIDE);
                    #pragma unroll
                    for (int nf = 0; nf < 4; nf++)
                        acc[mf][nf] = __builtin_amdgcn_mfma_f32_16x16x32_bf16(af, bf[nf], acc[mf][nf], 0, 0, 0);
                }
            }
        }
    }

    #pragma unroll
    for (int mf = 0; mf < 4; mf++) {
        if (mf < nmf) {
            #pragma unroll
            for (int j4 = 0; j4 < 4; j4++) {
                int r = band * 64 + mf * 16 + ((lane >> 4) << 2) + j4;
                if (r < count) {
                    unsigned short* yrow = ybh + (((size_t)(e * CAP + r)) << 10) + nb + nh * 64 + (lane & 15);
                    #pragma unroll
                    for (int nf = 0; nf < 4; nf++)
                        yrow[nf * 16] = f2bf(acc[mf][nf][j4]);
                }
            }
        }
    }
}

// ---------------- combine (unchanged) ----------------
__global__ __launch_bounds__(256) void combine_kernel(
    const unsigned short* __restrict__ ybh, const int* __restrict__ tokSlot,
    const float* __restrict__ tokGate, float* __restrict__ out)
{
    int tid = threadIdx.x;
    int tok = blockIdx.x * 4 + (tid >> 6);
    int lane = tid & 63;
    int sA = tokSlot[2 * tok], sB = tokSlot[2 * tok + 1];
    float gA = tokGate[2 * tok], gB = tokGate[2 * tok + 1];

    uint4 va[2] = {{0,0,0,0},{0,0,0,0}}, vb[2] = {{0,0,0,0},{0,0,0,0}};
    if (sA >= 0) {
        const uint4* p = (const uint4*)(ybh + ((size_t)sA << 10)) + lane * 2;
        va[0] = p[0]; va[1] = p[1];
    }
    if (sB >= 0) {
        const uint4* p = (const uint4*)(ybh + ((size_t)sB << 10)) + lane * 2;
        vb[0] = p[0]; vb[1] = p[1];
    }
    float4* o4 = (float4*)(out + ((size_t)tok << 10)) + lane * 4;
    #pragma unroll
    for (int h = 0; h < 2; h++) {
        const unsigned int* ua = (const unsigned int*)&va[h];
        const unsigned int* ub = (const unsigned int*)&vb[h];
        #pragma unroll
        for (int q = 0; q < 2; q++) {
            float4 o;
            unsigned int a0 = ua[q * 2], a1 = ua[q * 2 + 1];
            unsigned int b0 = ub[q * 2], b1 = ub[q * 2 + 1];
            o.x = gA * bf2f((unsigned short)(a0 & 0xFFFF)) + gB * bf2f((unsigned short)(b0 & 0xFFFF));
            o.y = gA * bf2f((unsigned short)(a0 >> 16))    + gB * bf2f((unsigned short)(b0 >> 16));
            o.z = gA * bf2f((unsigned short)(a1 & 0xFFFF)) + gB * bf2f((unsigned short)(b1 & 0xFFFF));
            o.w = gA * bf2f((unsigned short)(a1 >> 16))    + gB * bf2f((unsigned short)(b1 >> 16));
            o4[h * 2 + q] = o;
        }
    }
}

extern "C" void kernel_launch(void* const* d_in, const int* in_sizes, int n_in,
                              void* d_out, int out_size, void* d_ws, size_t ws_size,
                              hipStream_t stream) {
    const float* x  = (const float*)d_in[0];   // [4,2048,1024]
    const float* wg = (const float*)d_in[1];   // [1024,128]
    const float* we = (const float*)d_in[2];   // [128,1024,1024]
    float* out = (float*)d_out;                // [4,2048,1024]

    // Workspace map (4 KB guard gaps, no overlaps — R6's bug was tokGate/wgT overlap):
    char* ws = (char*)d_ws;
    int*   cnt     = (int*)(ws + 0);            // 512 B            [0, 512)
    int*   tokList = (int*)(ws + 4096);         // 128 KB           [4096, 135168)
    int*   tokSlot = (int*)(ws + 139264);       // 64 KB            [139264, 204800)
    float* tokGate = (float*)(ws + 208896);     // 64 KB            [208896, 274432)
    float* wgT     = (float*)(ws + 278528);     // 512 KB           [278528, 802816)
    unsigned short* xb  = (unsigned short*)(ws + 1048576);          // 16 MB  [1 MB, 17825792)
    unsigned short* ybh = (unsigned short*)(ws + 17825792);         // 64 MB  [17825792, 84934656)

    prep_kernel<<<2081, 256, 0, stream>>>(x, wg, xb, wgT, cnt);
    gate_mfma<<<128, 512, 0, stream>>>(x, wg, wgT, xb, cnt, tokList, tokSlot, tokGate);
    moe_gemm<<<1024, 512, 0, stream>>>(we, xb, cnt, tokList, ybh);
    combine_kernel<<<2048, 256, 0, stream>>>(ybh, tokSlot, tokGate, out);
}